// Round 18
// baseline (586.796 us; speedup 1.0000x reference)
//
#include <hip/hip_runtime.h>
#include <cstdint>
#include <cstddef>

#define N_NEU 2048
#define D_IN  1024
#define T_STEPS 64

typedef _Float16 f16x8 __attribute__((ext_vector_type(8)));
typedef _Float16 f16x4 __attribute__((ext_vector_type(4)));
typedef float    f32x4 __attribute__((ext_vector_type(4)));
typedef float    f32x16 __attribute__((ext_vector_type(16)));
typedef unsigned u32x4 __attribute__((ext_vector_type(4)));

#define MFMA32(a, b, c) __builtin_amdgcn_mfma_f32_32x32x16_f16((a), (b), (c), 0, 0, 0)

// ---------------- ws layout (bytes) ----------------
// Wh   [2048][2048] f16   @ 0       (8 MB)
// Wl   [2048][2048] f16   @ 8 MB    (8 MB)
// Iext [256][2048]  f32   @ 16 MB   (2 MB)
// bmv  u64[2][256][64]    @ 18 MB   (256 KB)  (tag<<32)|bits: word (row, n/32), bit n%32

// 8 bits -> 8 f16 (0.0/1.0) via multiply-spread: 4 VALU/word.
__device__ inline f16x8 expand8(unsigned b) {
  u32x4 t;
#pragma unroll
  for (int i = 0; i < 4; ++i) {
    unsigned m = (b >> (2 * i)) & 3u;
    unsigned s = (m | (m << 15)) & 0x00010001u;
    t[i] = s * 0x3C00u;
  }
  return __builtin_bit_cast(f16x8, t);
}

// Split W_eff = adj*mask into f16 hi + f16 lo' (w ~= hi + lo'/4096). Zeroes bmv (replay!).
__global__ __launch_bounds__(256) void k_wsplit(const float* __restrict__ adj,
                                                const float* __restrict__ mask,
                                                _Float16* __restrict__ Wh,
                                                _Float16* __restrict__ Wl,
                                                unsigned long long* __restrict__ bmv) {
  const int idx = blockIdx.x * 256 + threadIdx.x;
  if (idx < 2 * 256 * 64) bmv[idx] = 0ull;
  const int total4 = (N_NEU * N_NEU) / 4;
  for (int i = idx; i < total4; i += gridDim.x * 256) {
    float4 a = ((const float4*)adj)[i];
    float4 m = ((const float4*)mask)[i];
    float w0 = a.x * m.x, w1 = a.y * m.y, w2 = a.z * m.z, w3 = a.w * m.w;
    f16x4 h, lo;
    h[0] = (_Float16)w0; lo[0] = (_Float16)((w0 - (float)h[0]) * 4096.0f);
    h[1] = (_Float16)w1; lo[1] = (_Float16)((w1 - (float)h[1]) * 4096.0f);
    h[2] = (_Float16)w2; lo[2] = (_Float16)((w2 - (float)h[2]) * 4096.0f);
    h[3] = (_Float16)w3; lo[3] = (_Float16)((w3 - (float)h[3]) * 4096.0f);
    ((f16x4*)Wh)[i] = h;
    ((f16x4*)Wl)[i] = lo;
  }
}

// I_ext = ext @ W_in^T + b_in, plain fp32. Proven absmax 0.0 (r1/r5-r16).
__global__ __launch_bounds__(256) void k_iext(const float* __restrict__ ext,
                                              const float* __restrict__ Win,
                                              const float* __restrict__ bin,
                                              float* __restrict__ Iext) {
  __shared__ float At[32][68];
  __shared__ float Bt[32][68];
  const int tid = threadIdx.x;
  const int b0 = (blockIdx.x & 3) * 64;
  const int n0 = (blockIdx.x >> 2) * 64;
  const int tx = tid & 15, ty = tid >> 4;
  float acc[4][4] = {};
  for (int kt = 0; kt < D_IN / 32; ++kt) {
    const int k0 = kt * 32;
#pragma unroll
    for (int i = 0; i < 8; ++i) {
      int e = tid + i * 256;
      int kk = e & 31, row = e >> 5;
      At[kk][row] = ext[(size_t)(b0 + row) * D_IN + k0 + kk];
      Bt[kk][row] = Win[(size_t)(n0 + row) * D_IN + k0 + kk];
    }
    __syncthreads();
    for (int kk = 0; kk < 32; ++kk) {
      f32x4 a = *(const f32x4*)&At[kk][ty * 4];
      f32x4 b = *(const f32x4*)&Bt[kk][tx * 4];
#pragma unroll
      for (int i = 0; i < 4; ++i)
#pragma unroll
        for (int j = 0; j < 4; ++j) acc[i][j] += a[i] * b[j];
    }
    __syncthreads();
  }
#pragma unroll
  for (int i = 0; i < 4; ++i)
#pragma unroll
    for (int j = 0; j < 4; ++j)
      Iext[(size_t)(b0 + ty * 4 + i) * N_NEU + n0 + tx * 4 + j] = acc[i][j] + bin[n0 + tx * 4 + j];
}

// Persistent fused LIF kernel, dual-group zero-barrier dataflow (r16 structure) with
// 32x32x16 MFMA, TRUE register residency (waves_per_eu(2,2) -> 256-VGPR budget) and
// 4 independent accumulator chains.
// 256 blocks x 512 thr (1/CU). Block (gp 0..3, ns 0..63): groups gA=gp, gB=gp+4 (32 rows)
// x cols ns*32..+32. 8 waves split K (256 each).
__global__ __launch_bounds__(512, 2) __attribute__((amdgpu_waves_per_eu(2, 2)))
void k_fused15(
    const _Float16* __restrict__ Wh, const _Float16* __restrict__ Wl,
    const float* __restrict__ Iext, unsigned long long* __restrict__ bmv,
    float* __restrict__ out) {
  __shared__ float red[8 * 32 * 33];   // 33 KB: [wave][col][row], stride 33 (conflict-free)
  __shared__ unsigned bmA[32 * 64];    // 8 KB group-A spike bits (swizzled)
  __shared__ unsigned bmB[32 * 64];    // 8 KB group-B spike bits

  const int tid = threadIdx.x;
  const int lane = tid & 63;
  const int kw = tid >> 6;        // wave id = split-K index 0..7
  const int l31 = lane & 31;
  const int hl = lane >> 5;       // 0/1: k-half within MFMA
  const int gp = blockIdx.x >> 6; // 0..3
  const int ns = blockIdx.x & 63; // 0..63
  const int n0 = ns * 32;
  const int gA = gp, gB = gp + 4;
  const float inv4096 = 1.0f / 4096.0f;

  // ---------- per-thread Iext (mapping identical to r16) ----------
  float IxA[2], IxB[2];
#pragma unroll
  for (int j = 0; j < 2; ++j) {
    IxA[j] = Iext[(size_t)(gA * 32 + j * 16 + (tid >> 5)) * N_NEU + n0 + (tid & 31)];
    IxB[j] = Iext[(size_t)(gB * 32 + j * 16 + (tid >> 5)) * N_NEU + n0 + (tid & 31)];
  }

  // ---------- resident Wh + Wl fragments for 32x32x16 ----------
  // B layout: lane holds col = lane&31, k = (lane>>5)*8 + reg.
  const _Float16* whb = Wh + (size_t)(n0 + l31) * N_NEU + kw * 256 + hl * 8;
  const _Float16* wlb = Wl + (size_t)(n0 + l31) * N_NEU + kw * 256 + hl * 8;
  f16x8 whf[16], wlf[16];
#pragma unroll
  for (int kcl = 0; kcl < 16; ++kcl) {
    whf[kcl] = *(const f16x8*)(whb + kcl * 16);
    wlf[kcl] = *(const f16x8*)(wlb + kcl * 16);
  }

  float VA[2] = {0.f, 0.f}, VB[2] = {0.f, 0.f};
  unsigned cA[2] = {0u, 0u}, cB[2] = {0u, 0u};
  unsigned long long vA[4], vB[4];

  // speculative one-shot load of group g's 2048-word slab (4 coalesced u64/thread)
  auto spec_issue = [&](int g, int buf, unsigned long long (&v)[4]) {
    const unsigned long long* src = bmv + (size_t)buf * 16384 + (size_t)g * 2048 + tid;
#pragma unroll
    for (int i = 0; i < 4; ++i)
      v[i] = __hip_atomic_load(src + (size_t)i * 512, __ATOMIC_RELAXED, __HIP_MEMORY_SCOPE_AGENT);
  };
  // validate tags; retry only stale words (rare: issued a compute-phase ago)
  auto check_retry = [&](int g, int buf, unsigned want, unsigned long long (&v)[4]) {
    const unsigned long long* src = bmv + (size_t)buf * 16384 + (size_t)g * 2048 + tid;
    unsigned need = 0u;
#pragma unroll
    for (int i = 0; i < 4; ++i)
      if ((unsigned)(v[i] >> 32) != want) need |= 1u << i;
    while (need) {
      __builtin_amdgcn_s_sleep(2);
#pragma unroll
      for (int i = 0; i < 4; ++i)
        if (need & (1u << i)) {
          v[i] = __hip_atomic_load(src + (size_t)i * 512,
                                   __ATOMIC_RELAXED, __HIP_MEMORY_SCOPE_AGENT);
          if ((unsigned)(v[i] >> 32) == want) need &= ~(1u << i);
        }
    }
  };
  // stage bits into swizzled LDS: word nsw of row r at [r*64 + (nsw ^ ((r&15)<<2))]
  auto stage = [&](unsigned* bm, const unsigned long long (&v)[4]) {
#pragma unroll
    for (int i = 0; i < 4; ++i) {
      const int w = i * 512 + tid, r = w >> 6, nsw = w & 63;
      bm[r * 64 + (nsw ^ ((r & 15) << 2))] = (unsigned)v[i];
    }
  };
  // K-loop (32x32x16, 16 kcl x 2 terms, 4 chains) + flat 8-slab tree (ONE sync) -> cI[2]
  auto gemm = [&](const unsigned* bm, float (&cI)[2]) {
    const f32x16 z16 = {0.f, 0.f, 0.f, 0.f, 0.f, 0.f, 0.f, 0.f,
                        0.f, 0.f, 0.f, 0.f, 0.f, 0.f, 0.f, 0.f};
    f32x16 acch0 = z16, acch1 = z16, accl0 = z16, accl1 = z16;
    // A bits: row = lane&31, k-byte(kcl) = 2*kcl + hl -> word kcl>>1, shift hl*8+(kcl&1)*16
    const int arow = l31;
    const int swz = (arow & 15) << 2;
    const u32x4 q0 = *(const u32x4*)&bm[arow * 64 + ((kw * 8) ^ swz)];
    const u32x4 q1 = *(const u32x4*)&bm[arow * 64 + (((kw * 8) | 4) ^ swz)];
    const unsigned sh0 = hl * 8;
#pragma unroll
    for (int kc2 = 0; kc2 < 8; ++kc2) {
      const int ke = 2 * kc2, ko = 2 * kc2 + 1;
      const unsigned we = (ke < 8) ? q0[ke >> 1] : q1[(ke >> 1) - 4];
      const f16x8 ae = expand8((we >> (sh0 + ((ke & 1) << 4))) & 0xFFu);
      acch0 = MFMA32(ae, whf[ke], acch0);
      accl0 = MFMA32(ae, wlf[ke], accl0);
      const unsigned wo = (ko < 8) ? q0[ko >> 1] : q1[(ko >> 1) - 4];
      const f16x8 ao = expand8((wo >> (sh0 + ((ko & 1) << 4))) & 0xFFu);
      acch1 = MFMA32(ao, whf[ko], acch1);
      accl1 = MFMA32(ao, wlf[ko], accl1);
    }
    f32x16 cb = (acch0 + acch1) + (accl0 + accl1) * inv4096;
    // C layout: col = lane&31, row = (reg&3) + 8*(reg>>2) + 4*hl
    const int hl4 = hl * 4;
#pragma unroll
    for (int rg = 0; rg < 4; ++rg) {
      f32x4 part = {cb[rg * 4 + 0], cb[rg * 4 + 1], cb[rg * 4 + 2], cb[rg * 4 + 3]};
      *(f32x4*)&red[(kw * 32 + l31) * 33 + rg * 8 + hl4] = part;
    }
    __syncthreads();
#pragma unroll
    for (int j = 0; j < 2; ++j) {
      const int o = j * 512 + tid;
      const int row = o >> 5, col = o & 31;
      float s = 0.0f;
#pragma unroll
      for (int p = 0; p < 8; ++p) s += red[(p * 32 + col) * 33 + row];
      cI[j] = s;
    }
  };
  // LIF + tagged spike stores (tag and bits in ONE u64: single-copy-atomic)
  auto lif = [&](const float (&cI)[2], const float (&Ix)[2], float (&V)[2],
                 unsigned (&cnt)[2], int g, int nbuf, unsigned tag, bool dostore) {
#pragma unroll
    for (int j = 0; j < 2; ++j) {
      float I = cI[j] + Ix[j];
      float v = 0.9f * V[j] + I;
      bool sp = (v - 1.0f) >= 0.0f;
      V[j] = sp ? 0.0f : v;
      cnt[j] += sp ? 1u : 0u;
      if (dostore) {
        unsigned long long ba = __ballot(sp);
        const int rowf = g * 32 + j * 16 + kw * 2;  // lanes 0-31: rowf, 32-63: rowf+1
        const unsigned long long tg = ((unsigned long long)tag) << 32;
        if (lane == 0)
          __hip_atomic_store(bmv + (size_t)nbuf * 16384 + (size_t)rowf * 64 + ns,
                             tg | (unsigned)ba, __ATOMIC_RELAXED, __HIP_MEMORY_SCOPE_AGENT);
        else if (lane == 32)
          __hip_atomic_store(bmv + (size_t)nbuf * 16384 + (size_t)(rowf + 1) * 64 + ns,
                             tg | (unsigned)(ba >> 32), __ATOMIC_RELAXED, __HIP_MEMORY_SCOPE_AGENT);
      }
    }
  };

  // ---------- t = 0: Iext-only LIF; spikes tagged 1 -> buf 1; prefetch A ----------
  {
    const float cz[2] = {0.f, 0.f};
    lif(cz, IxA, VA, cA, gA, 1, 1u, true);
    lif(cz, IxB, VB, cB, gB, 1, 1u, true);
    spec_issue(gA, 1, vA);
  }

  for (int t = 1; t < T_STEPS; ++t) {
    const int cbuf = t & 1, nbuf = (t + 1) & 1;
    const bool last = (t == T_STEPS - 1);
    float cI[2];

    // ---- phase A ----
    check_retry(gA, cbuf, (unsigned)t, vA);
    stage(bmA, vA);
    __syncthreads();
    spec_issue(gB, cbuf, vB);            // in flight under gemm(A)
    gemm(bmA, cI);
    lif(cI, IxA, VA, cA, gA, nbuf, (unsigned)(t + 1), !last);

    // ---- phase B ----
    check_retry(gB, cbuf, (unsigned)t, vB);
    stage(bmB, vB);
    __syncthreads();
    if (!last) spec_issue(gA, nbuf, vA); // in flight under gemm(B)
    gemm(bmB, cI);
    lif(cI, IxB, VB, cB, gB, nbuf, (unsigned)(t + 1), !last);
  }

  // ---------- write firing rates ----------
#pragma unroll
  for (int j = 0; j < 2; ++j) {
    const int rA = gA * 32 + j * 16 + (tid >> 5);
    const int rB = gB * 32 + j * 16 + (tid >> 5);
    out[(size_t)rA * N_NEU + n0 + (tid & 31)] = (float)cA[j] * 0.015625f;
    out[(size_t)rB * N_NEU + n0 + (tid & 31)] = (float)cB[j] * 0.015625f;
  }
}

extern "C" void kernel_launch(void* const* d_in, const int* in_sizes, int n_in,
                              void* d_out, int out_size, void* d_ws, size_t ws_size,
                              hipStream_t stream) {
  (void)in_sizes; (void)n_in; (void)out_size; (void)ws_size;
  const float* ext  = (const float*)d_in[0];
  const float* Win  = (const float*)d_in[1];
  const float* bin  = (const float*)d_in[2];
  const float* adj  = (const float*)d_in[3];
  const float* mask = (const float*)d_in[4];
  unsigned char* ws = (unsigned char*)d_ws;

  _Float16* Wh   = (_Float16*)(ws);
  _Float16* Wl   = (_Float16*)(ws + (size_t)(8u << 20));
  float*    Iext = (float*)   (ws + (size_t)(16u << 20));
  unsigned long long* bmv = (unsigned long long*)(ws + (size_t)(18u << 20));
  float* out = (float*)d_out;

  hipLaunchKernelGGL(k_wsplit, dim3(2048), dim3(256), 0, stream, adj, mask, Wh, Wl, bmv);
  hipLaunchKernelGGL(k_iext,   dim3(128),  dim3(256), 0, stream, ext, Win, bin, Iext);
  hipLaunchKernelGGL(k_fused15, dim3(256), dim3(512), 0, stream,
                     Wh, Wl, Iext, bmv, out);
}

// Round 19
// 510.214 us; speedup vs baseline: 1.1501x; 1.1501x over previous
//
#include <hip/hip_runtime.h>
#include <cstdint>
#include <cstddef>

#define N_NEU 2048
#define D_IN  1024
#define T_STEPS 64

typedef _Float16 f16x8 __attribute__((ext_vector_type(8)));
typedef _Float16 f16x4 __attribute__((ext_vector_type(4)));
typedef float    f32x4 __attribute__((ext_vector_type(4)));
typedef float    f32x16 __attribute__((ext_vector_type(16)));
typedef unsigned u32x4 __attribute__((ext_vector_type(4)));

#define MFMA32(a, b, c) __builtin_amdgcn_mfma_f32_32x32x16_f16((a), (b), (c), 0, 0, 0)

// ---------------- ws layout (bytes) ----------------
// Wh   [2048][2048] f16   @ 0       (8 MB)
// Wl   [2048][2048] f16   @ 8 MB    (8 MB)
// Iext [256][2048]  f32   @ 16 MB   (2 MB)
// bmv  u64[2][256][64]    @ 18 MB   (256 KB)  (tag<<32)|bits: word (row, n/32), bit n%32

// 8 bits -> 8 f16 (0.0/1.0) via multiply-spread: 4 VALU/word.
__device__ inline f16x8 expand8(unsigned b) {
  u32x4 t;
#pragma unroll
  for (int i = 0; i < 4; ++i) {
    unsigned m = (b >> (2 * i)) & 3u;
    unsigned s = (m | (m << 15)) & 0x00010001u;
    t[i] = s * 0x3C00u;
  }
  return __builtin_bit_cast(f16x8, t);
}

// Split W_eff = adj*mask into f16 hi + f16 lo' (w ~= hi + lo'/4096). Zeroes bmv (replay!).
__global__ __launch_bounds__(256) void k_wsplit(const float* __restrict__ adj,
                                                const float* __restrict__ mask,
                                                _Float16* __restrict__ Wh,
                                                _Float16* __restrict__ Wl,
                                                unsigned long long* __restrict__ bmv) {
  const int idx = blockIdx.x * 256 + threadIdx.x;
  if (idx < 2 * 256 * 64) bmv[idx] = 0ull;
  const int total4 = (N_NEU * N_NEU) / 4;
  for (int i = idx; i < total4; i += gridDim.x * 256) {
    float4 a = ((const float4*)adj)[i];
    float4 m = ((const float4*)mask)[i];
    float w0 = a.x * m.x, w1 = a.y * m.y, w2 = a.z * m.z, w3 = a.w * m.w;
    f16x4 h, lo;
    h[0] = (_Float16)w0; lo[0] = (_Float16)((w0 - (float)h[0]) * 4096.0f);
    h[1] = (_Float16)w1; lo[1] = (_Float16)((w1 - (float)h[1]) * 4096.0f);
    h[2] = (_Float16)w2; lo[2] = (_Float16)((w2 - (float)h[2]) * 4096.0f);
    h[3] = (_Float16)w3; lo[3] = (_Float16)((w3 - (float)h[3]) * 4096.0f);
    ((f16x4*)Wh)[i] = h;
    ((f16x4*)Wl)[i] = lo;
  }
}

// I_ext = ext @ W_in^T + b_in, plain fp32. Proven absmax 0.0 (r1/r5-r18).
__global__ __launch_bounds__(256) void k_iext(const float* __restrict__ ext,
                                              const float* __restrict__ Win,
                                              const float* __restrict__ bin,
                                              float* __restrict__ Iext) {
  __shared__ float At[32][68];
  __shared__ float Bt[32][68];
  const int tid = threadIdx.x;
  const int b0 = (blockIdx.x & 3) * 64;
  const int n0 = (blockIdx.x >> 2) * 64;
  const int tx = tid & 15, ty = tid >> 4;
  float acc[4][4] = {};
  for (int kt = 0; kt < D_IN / 32; ++kt) {
    const int k0 = kt * 32;
#pragma unroll
    for (int i = 0; i < 8; ++i) {
      int e = tid + i * 256;
      int kk = e & 31, row = e >> 5;
      At[kk][row] = ext[(size_t)(b0 + row) * D_IN + k0 + kk];
      Bt[kk][row] = Win[(size_t)(n0 + row) * D_IN + k0 + kk];
    }
    __syncthreads();
    for (int kk = 0; kk < 32; ++kk) {
      f32x4 a = *(const f32x4*)&At[kk][ty * 4];
      f32x4 b = *(const f32x4*)&Bt[kk][tx * 4];
#pragma unroll
      for (int i = 0; i < 4; ++i)
#pragma unroll
        for (int j = 0; j < 4; ++j) acc[i][j] += a[i] * b[j];
    }
    __syncthreads();
  }
#pragma unroll
  for (int i = 0; i < 4; ++i)
#pragma unroll
    for (int j = 0; j < 4; ++j)
      Iext[(size_t)(b0 + ty * 4 + i) * N_NEU + n0 + tx * 4 + j] = acc[i][j] + bin[n0 + tx * 4 + j];
}

// Persistent fused LIF kernel: dual-group zero-barrier dataflow with TRUE W residency.
// 256 blocks x 256 thr (4 waves = 1 wave/SIMD -> 512-VGPR budget via launch_bounds(256,1)).
// Block (gp 0..3, ns 0..63): groups gA=gp (rows gp*32..+32), gB=gp+4 x cols ns*32..+32.
// 4 waves split K (512 each): W fragments = 64 x f16x8 = 256 VGPRs, held in registers.
__global__ __launch_bounds__(256, 1) void k_fused16(
    const _Float16* __restrict__ Wh, const _Float16* __restrict__ Wl,
    const float* __restrict__ Iext, unsigned long long* __restrict__ bmv,
    float* __restrict__ out) {
  __shared__ float red[4 * 32 * 33];   // 16.9 KB: [wave][col][row], stride 33
  __shared__ unsigned bmA[32 * 64];    // 8 KB group-A spike bits (swizzled)
  __shared__ unsigned bmB[32 * 64];    // 8 KB group-B spike bits

  const int tid = threadIdx.x;
  const int lane = tid & 63;
  const int kw = tid >> 6;        // wave id = split-K index 0..3 (512 K each)
  const int l31 = lane & 31;
  const int hl = lane >> 5;       // 0/1: k-half within a 16-K MFMA tile
  const int gp = blockIdx.x >> 6; // 0..3
  const int ns = blockIdx.x & 63; // 0..63
  const int n0 = ns * 32;
  const int gA = gp, gB = gp + 4;
  const float inv4096 = 1.0f / 4096.0f;

  // ---------- per-thread Iext: 4 output rows per thread per group ----------
  float IxA[4], IxB[4];
#pragma unroll
  for (int j = 0; j < 4; ++j) {
    IxA[j] = Iext[(size_t)(gA * 32 + j * 8 + (tid >> 5)) * N_NEU + n0 + (tid & 31)];
    IxB[j] = Iext[(size_t)(gB * 32 + j * 8 + (tid >> 5)) * N_NEU + n0 + (tid & 31)];
  }

  // ---------- resident Wh + Wl fragments (256 VGPRs, k = kw*512 + kcl*16 + hl*8 + reg) ----------
  const _Float16* whb = Wh + (size_t)(n0 + l31) * N_NEU + kw * 512 + hl * 8;
  const _Float16* wlb = Wl + (size_t)(n0 + l31) * N_NEU + kw * 512 + hl * 8;
  f16x8 whf[32], wlf[32];
#pragma unroll
  for (int kcl = 0; kcl < 32; ++kcl) {
    whf[kcl] = *(const f16x8*)(whb + kcl * 16);
    wlf[kcl] = *(const f16x8*)(wlb + kcl * 16);
  }

  float VA[4] = {0.f, 0.f, 0.f, 0.f}, VB[4] = {0.f, 0.f, 0.f, 0.f};
  unsigned cA[4] = {0u, 0u, 0u, 0u}, cB[4] = {0u, 0u, 0u, 0u};
  unsigned long long vA[8], vB[8];

  // speculative one-shot load of group g's 2048-u64 slab (8 coalesced u64/thread)
  auto spec_issue = [&](int g, int buf, unsigned long long (&v)[8]) {
    const unsigned long long* src = bmv + (size_t)buf * 16384 + (size_t)g * 2048 + tid;
#pragma unroll
    for (int i = 0; i < 8; ++i)
      v[i] = __hip_atomic_load(src + (size_t)i * 256, __ATOMIC_RELAXED, __HIP_MEMORY_SCOPE_AGENT);
  };
  // validate tags; retry only stale words (rare: issued a compute-phase ago)
  auto check_retry = [&](int g, int buf, unsigned want, unsigned long long (&v)[8]) {
    const unsigned long long* src = bmv + (size_t)buf * 16384 + (size_t)g * 2048 + tid;
    unsigned need = 0u;
#pragma unroll
    for (int i = 0; i < 8; ++i)
      if ((unsigned)(v[i] >> 32) != want) need |= 1u << i;
    while (need) {
      __builtin_amdgcn_s_sleep(2);
#pragma unroll
      for (int i = 0; i < 8; ++i)
        if (need & (1u << i)) {
          v[i] = __hip_atomic_load(src + (size_t)i * 256,
                                   __ATOMIC_RELAXED, __HIP_MEMORY_SCOPE_AGENT);
          if ((unsigned)(v[i] >> 32) == want) need &= ~(1u << i);
        }
    }
  };
  // stage bits into swizzled LDS: word nsw of row r at [r*64 + (nsw ^ ((r&15)<<2))]
  auto stage = [&](unsigned* bm, const unsigned long long (&v)[8]) {
#pragma unroll
    for (int i = 0; i < 8; ++i) {
      const int w = i * 256 + tid, r = w >> 6, nsw = w & 63;
      bm[r * 64 + (nsw ^ ((r & 15) << 2))] = (unsigned)v[i];
    }
  };
  // K-loop (32x32x16, 32 kcl x 2 terms, pure-register W) + 4-slab tree (ONE sync) -> cI[4]
  auto gemm = [&](const unsigned* bm, float (&cI)[4]) {
    const f32x16 z16 = {0.f, 0.f, 0.f, 0.f, 0.f, 0.f, 0.f, 0.f,
                        0.f, 0.f, 0.f, 0.f, 0.f, 0.f, 0.f, 0.f};
    f32x16 acch = z16, accl = z16;
    // A bits: row = l31, byte (in row's 256-byte K-bitmap) = kw*64 + kcl*2 + hl
    const int swz = (l31 & 15) << 2;
    unsigned q[16];
#pragma unroll
    for (int jq = 0; jq < 4; ++jq) {
      const u32x4 qq = *(const u32x4*)&bm[l31 * 64 + ((kw * 16 + jq * 4) ^ swz)];
      q[jq * 4 + 0] = qq[0]; q[jq * 4 + 1] = qq[1];
      q[jq * 4 + 2] = qq[2]; q[jq * 4 + 3] = qq[3];
    }
    __builtin_amdgcn_s_setprio(1);
#pragma unroll
    for (int kcl = 0; kcl < 32; ++kcl) {
      const int bl = kcl * 2 + hl;                  // local byte index 0..63
      const f16x8 a = expand8((q[bl >> 2] >> ((bl & 3) * 8)) & 0xFFu);
      acch = MFMA32(a, whf[kcl], acch);
      accl = MFMA32(a, wlf[kcl], accl);
    }
    __builtin_amdgcn_s_setprio(0);
    f32x16 cb = acch + accl * inv4096;
    // C layout: col = lane&31, row = (reg&3) + 8*(reg>>2) + 4*hl
    const int hl4 = hl * 4;
#pragma unroll
    for (int rg = 0; rg < 4; ++rg) {
      f32x4 part = {cb[rg * 4 + 0], cb[rg * 4 + 1], cb[rg * 4 + 2], cb[rg * 4 + 3]};
      *(f32x4*)&red[(kw * 32 + l31) * 33 + rg * 8 + hl4] = part;
    }
    __syncthreads();
#pragma unroll
    for (int j = 0; j < 4; ++j) {
      const int o = j * 256 + tid;
      const int row = o >> 5, col = o & 31;
      float s = 0.0f;
#pragma unroll
      for (int p = 0; p < 4; ++p) s += red[(p * 32 + col) * 33 + row];
      cI[j] = s;
    }
  };
  // LIF + tagged spike stores (tag and bits in ONE u64: single-copy-atomic)
  auto lif = [&](const float (&cI)[4], const float (&Ix)[4], float (&V)[4],
                 unsigned (&cnt)[4], int g, int nbuf, unsigned tag, bool dostore) {
#pragma unroll
    for (int j = 0; j < 4; ++j) {
      float I = cI[j] + Ix[j];
      float v = 0.9f * V[j] + I;
      bool sp = (v - 1.0f) >= 0.0f;
      V[j] = sp ? 0.0f : v;
      cnt[j] += sp ? 1u : 0u;
      if (dostore) {
        unsigned long long ba = __ballot(sp);
        const int rowf = g * 32 + j * 8 + kw * 2;   // lanes 0-31: rowf, 32-63: rowf+1
        const unsigned long long tg = ((unsigned long long)tag) << 32;
        if (lane == 0)
          __hip_atomic_store(bmv + (size_t)nbuf * 16384 + (size_t)rowf * 64 + ns,
                             tg | (unsigned)ba, __ATOMIC_RELAXED, __HIP_MEMORY_SCOPE_AGENT);
        else if (lane == 32)
          __hip_atomic_store(bmv + (size_t)nbuf * 16384 + (size_t)(rowf + 1) * 64 + ns,
                             tg | (unsigned)(ba >> 32), __ATOMIC_RELAXED, __HIP_MEMORY_SCOPE_AGENT);
      }
    }
  };

  // ---------- t = 0: Iext-only LIF; spikes tagged 1 -> buf 1; prefetch A ----------
  {
    const float cz[4] = {0.f, 0.f, 0.f, 0.f};
    lif(cz, IxA, VA, cA, gA, 1, 1u, true);
    lif(cz, IxB, VB, cB, gB, 1, 1u, true);
    spec_issue(gA, 1, vA);
  }

  for (int t = 1; t < T_STEPS; ++t) {
    const int cbuf = t & 1, nbuf = (t + 1) & 1;
    const bool last = (t == T_STEPS - 1);
    float cI[4];

    // ---- phase A ----
    check_retry(gA, cbuf, (unsigned)t, vA);
    stage(bmA, vA);
    __syncthreads();
    spec_issue(gB, cbuf, vB);            // in flight under gemm(A)
    gemm(bmA, cI);
    lif(cI, IxA, VA, cA, gA, nbuf, (unsigned)(t + 1), !last);

    // ---- phase B ----
    check_retry(gB, cbuf, (unsigned)t, vB);
    stage(bmB, vB);
    __syncthreads();
    if (!last) spec_issue(gA, nbuf, vA); // in flight under gemm(B)
    gemm(bmB, cI);
    lif(cI, IxB, VB, cB, gB, nbuf, (unsigned)(t + 1), !last);
  }

  // ---------- write firing rates ----------
#pragma unroll
  for (int j = 0; j < 4; ++j) {
    const int rA = gA * 32 + j * 8 + (tid >> 5);
    const int rB = gB * 32 + j * 8 + (tid >> 5);
    out[(size_t)rA * N_NEU + n0 + (tid & 31)] = (float)cA[j] * 0.015625f;
    out[(size_t)rB * N_NEU + n0 + (tid & 31)] = (float)cB[j] * 0.015625f;
  }
}

extern "C" void kernel_launch(void* const* d_in, const int* in_sizes, int n_in,
                              void* d_out, int out_size, void* d_ws, size_t ws_size,
                              hipStream_t stream) {
  (void)in_sizes; (void)n_in; (void)out_size; (void)ws_size;
  const float* ext  = (const float*)d_in[0];
  const float* Win  = (const float*)d_in[1];
  const float* bin  = (const float*)d_in[2];
  const float* adj  = (const float*)d_in[3];
  const float* mask = (const float*)d_in[4];
  unsigned char* ws = (unsigned char*)d_ws;

  _Float16* Wh   = (_Float16*)(ws);
  _Float16* Wl   = (_Float16*)(ws + (size_t)(8u << 20));
  float*    Iext = (float*)   (ws + (size_t)(16u << 20));
  unsigned long long* bmv = (unsigned long long*)(ws + (size_t)(18u << 20));
  float* out = (float*)d_out;

  hipLaunchKernelGGL(k_wsplit, dim3(2048), dim3(256), 0, stream, adj, mask, Wh, Wl, bmv);
  hipLaunchKernelGGL(k_iext,   dim3(128),  dim3(256), 0, stream, ext, Win, bin, Iext);
  hipLaunchKernelGGL(k_fused16, dim3(256), dim3(256), 0, stream,
                     Wh, Wl, Iext, bmv, out);
}

// Round 20
// 436.361 us; speedup vs baseline: 1.3447x; 1.1692x over previous
//
#include <hip/hip_runtime.h>
#include <cstdint>
#include <cstddef>

#define N_NEU 2048
#define D_IN  1024
#define T_STEPS 64

typedef _Float16 f16x8 __attribute__((ext_vector_type(8)));
typedef _Float16 f16x4 __attribute__((ext_vector_type(4)));
typedef float    f32x4 __attribute__((ext_vector_type(4)));
typedef float    f32x16 __attribute__((ext_vector_type(16)));
typedef unsigned u32x4 __attribute__((ext_vector_type(4)));

#define MFMA32(a, b, c) __builtin_amdgcn_mfma_f32_32x32x16_f16((a), (b), (c), 0, 0, 0)

// ---------------- ws layout (bytes) ----------------
// Wh   [2048][2048] f16   @ 0       (8 MB)
// Wl   [2048][2048] f16   @ 8 MB    (8 MB)
// Iext [256][2048]  f32   @ 16 MB   (2 MB)
// bmv  u64[2][256][64]    @ 18 MB   (256 KB)  (tag<<32)|bits: word (row, n/32), bit n%32

// 8 bits -> 8 f16 (0.0/1.0) via multiply-spread: 4 VALU/word.
__device__ inline f16x8 expand8(unsigned b) {
  u32x4 t;
#pragma unroll
  for (int i = 0; i < 4; ++i) {
    unsigned m = (b >> (2 * i)) & 3u;
    unsigned s = (m | (m << 15)) & 0x00010001u;
    t[i] = s * 0x3C00u;
  }
  return __builtin_bit_cast(f16x8, t);
}

// Split W_eff = adj*mask into f16 hi + f16 lo' (w ~= hi + lo'/4096). Zeroes bmv (replay!).
__global__ __launch_bounds__(256) void k_wsplit(const float* __restrict__ adj,
                                                const float* __restrict__ mask,
                                                _Float16* __restrict__ Wh,
                                                _Float16* __restrict__ Wl,
                                                unsigned long long* __restrict__ bmv) {
  const int idx = blockIdx.x * 256 + threadIdx.x;
  if (idx < 2 * 256 * 64) bmv[idx] = 0ull;
  const int total4 = (N_NEU * N_NEU) / 4;
  for (int i = idx; i < total4; i += gridDim.x * 256) {
    float4 a = ((const float4*)adj)[i];
    float4 m = ((const float4*)mask)[i];
    float w0 = a.x * m.x, w1 = a.y * m.y, w2 = a.z * m.z, w3 = a.w * m.w;
    f16x4 h, lo;
    h[0] = (_Float16)w0; lo[0] = (_Float16)((w0 - (float)h[0]) * 4096.0f);
    h[1] = (_Float16)w1; lo[1] = (_Float16)((w1 - (float)h[1]) * 4096.0f);
    h[2] = (_Float16)w2; lo[2] = (_Float16)((w2 - (float)h[2]) * 4096.0f);
    h[3] = (_Float16)w3; lo[3] = (_Float16)((w3 - (float)h[3]) * 4096.0f);
    ((f16x4*)Wh)[i] = h;
    ((f16x4*)Wl)[i] = lo;
  }
}

// I_ext = ext @ W_in^T + b_in, plain fp32. Proven absmax 0.0 (r1/r5-r19).
__global__ __launch_bounds__(256) void k_iext(const float* __restrict__ ext,
                                              const float* __restrict__ Win,
                                              const float* __restrict__ bin,
                                              float* __restrict__ Iext) {
  __shared__ float At[32][68];
  __shared__ float Bt[32][68];
  const int tid = threadIdx.x;
  const int b0 = (blockIdx.x & 3) * 64;
  const int n0 = (blockIdx.x >> 2) * 64;
  const int tx = tid & 15, ty = tid >> 4;
  float acc[4][4] = {};
  for (int kt = 0; kt < D_IN / 32; ++kt) {
    const int k0 = kt * 32;
#pragma unroll
    for (int i = 0; i < 8; ++i) {
      int e = tid + i * 256;
      int kk = e & 31, row = e >> 5;
      At[kk][row] = ext[(size_t)(b0 + row) * D_IN + k0 + kk];
      Bt[kk][row] = Win[(size_t)(n0 + row) * D_IN + k0 + kk];
    }
    __syncthreads();
    for (int kk = 0; kk < 32; ++kk) {
      f32x4 a = *(const f32x4*)&At[kk][ty * 4];
      f32x4 b = *(const f32x4*)&Bt[kk][tx * 4];
#pragma unroll
      for (int i = 0; i < 4; ++i)
#pragma unroll
        for (int j = 0; j < 4; ++j) acc[i][j] += a[i] * b[j];
    }
    __syncthreads();
  }
#pragma unroll
  for (int i = 0; i < 4; ++i)
#pragma unroll
    for (int j = 0; j < 4; ++j)
      Iext[(size_t)(b0 + ty * 4 + i) * N_NEU + n0 + tx * 4 + j] = acc[i][j] + bin[n0 + tx * 4 + j];
}

// Persistent fused LIF kernel (r16 structure) with ON-CHIP W residency:
// Wh in LDS (128 KB, [k8][col][8] f16, conflict-free b128 reads), Wl in VGPRs (64/wave).
// red/bm share one 32 KB pool (aliased; bm dead after q-load, enforced by sync).
// 256 blocks x 512 thr (1/CU). Block (gp 0..3, ns 0..63): groups gA=gp, gB=gp+4 (32 rows)
// x cols ns*32..+32. 8 waves split K (256 each). 32x32x16 MFMA.
__global__ __launch_bounds__(512, 2) void k_fused17(
    const _Float16* __restrict__ Wh, const _Float16* __restrict__ Wl,
    const float* __restrict__ Iext, unsigned long long* __restrict__ bmv,
    float* __restrict__ out) {
  __shared__ _Float16 WhL[65536];   // 128 KB: [k8 0..255][col 0..31][8 f16]
  __shared__ float pool[8192];      // 32 KB: bm region (first 8 KB) + red (full, aliased)

  const int tid = threadIdx.x;
  const int lane = tid & 63;
  const int kw = tid >> 6;        // wave id = split-K index 0..7
  const int l31 = lane & 31;
  const int hl = lane >> 5;       // 0/1: k-half within a 16-K MFMA tile
  const int gp = blockIdx.x >> 6; // 0..3
  const int ns = blockIdx.x & 63; // 0..63
  const int n0 = ns * 32;
  const int gA = gp, gB = gp + 4;
  const float inv4096 = 1.0f / 4096.0f;
  unsigned* bm = (unsigned*)pool;   // [32 rows][64 words], swizzled (first 8 KB)

  // ---------- one-time: load Wh slice into LDS (coalesced global, scattered LDS) ----------
#pragma unroll
  for (int i = 0; i < 16; ++i) {
    const int c = i * 512 + tid;            // c = col*256 + k8
    const int col = c >> 8, k8 = c & 255;
    ((f16x8*)WhL)[k8 * 32 + col] = *(const f16x8*)(Wh + (size_t)(n0 + col) * N_NEU + k8 * 8);
  }

  // ---------- per-thread Iext (mapping identical to r16) ----------
  float IxA[2], IxB[2];
#pragma unroll
  for (int j = 0; j < 2; ++j) {
    IxA[j] = Iext[(size_t)(gA * 32 + j * 16 + (tid >> 5)) * N_NEU + n0 + (tid & 31)];
    IxB[j] = Iext[(size_t)(gB * 32 + j * 16 + (tid >> 5)) * N_NEU + n0 + (tid & 31)];
  }

  // ---------- resident Wl fragments (64 VGPRs; k = kw*256 + kcl*16 + hl*8 + reg) ----------
  const _Float16* wlb = Wl + (size_t)(n0 + l31) * N_NEU + kw * 256 + hl * 8;
  f16x8 wlf[16];
#pragma unroll
  for (int kcl = 0; kcl < 16; ++kcl) wlf[kcl] = *(const f16x8*)(wlb + kcl * 16);

  float VA[2] = {0.f, 0.f}, VB[2] = {0.f, 0.f};
  unsigned cA[2] = {0u, 0u}, cB[2] = {0u, 0u};
  unsigned long long vA[4], vB[4];

  // speculative one-shot load of group g's 2048-word slab (4 coalesced u64/thread)
  auto spec_issue = [&](int g, int buf, unsigned long long (&v)[4]) {
    const unsigned long long* src = bmv + (size_t)buf * 16384 + (size_t)g * 2048 + tid;
#pragma unroll
    for (int i = 0; i < 4; ++i)
      v[i] = __hip_atomic_load(src + (size_t)i * 512, __ATOMIC_RELAXED, __HIP_MEMORY_SCOPE_AGENT);
  };
  // validate tags; retry only stale words (rare: issued a compute-phase ago)
  auto check_retry = [&](int g, int buf, unsigned want, unsigned long long (&v)[4]) {
    const unsigned long long* src = bmv + (size_t)buf * 16384 + (size_t)g * 2048 + tid;
    unsigned need = 0u;
#pragma unroll
    for (int i = 0; i < 4; ++i)
      if ((unsigned)(v[i] >> 32) != want) need |= 1u << i;
    while (need) {
      __builtin_amdgcn_s_sleep(2);
#pragma unroll
      for (int i = 0; i < 4; ++i)
        if (need & (1u << i)) {
          v[i] = __hip_atomic_load(src + (size_t)i * 512,
                                   __ATOMIC_RELAXED, __HIP_MEMORY_SCOPE_AGENT);
          if ((unsigned)(v[i] >> 32) == want) need &= ~(1u << i);
        }
    }
  };
  // stage bits into swizzled bm: word nsw of row r at [r*64 + (nsw ^ ((r&15)<<2))]
  auto stage = [&](const unsigned long long (&v)[4]) {
#pragma unroll
    for (int i = 0; i < 4; ++i) {
      const int w = i * 512 + tid, r = w >> 6, nsw = w & 63;
      bm[r * 64 + (nsw ^ ((r & 15) << 2))] = (unsigned)v[i];
    }
  };
  // K-loop (Wh from LDS, Wl from regs) + flat 8-slab XOR-32 tree -> cI[2]. 2 syncs inside.
  auto gemm = [&](float (&cI)[2]) {
    const f32x16 z16 = {0.f, 0.f, 0.f, 0.f, 0.f, 0.f, 0.f, 0.f,
                        0.f, 0.f, 0.f, 0.f, 0.f, 0.f, 0.f, 0.f};
    f32x16 acch = z16, accl = z16;
    // A bits (r16-verbatim): row = l31, word q[kcl>>1], shift hl*8 + (kcl&1)*16
    const int swz = (l31 & 15) << 2;
    const u32x4 q0 = *(const u32x4*)&bm[l31 * 64 + ((kw * 8) ^ swz)];
    const u32x4 q1 = *(const u32x4*)&bm[l31 * 64 + (((kw * 8) | 4) ^ swz)];
    const unsigned sh0 = hl * 8;
    __syncthreads();   // all q consumed; pool free for red
    __builtin_amdgcn_s_setprio(1);
#pragma unroll
    for (int kcl = 0; kcl < 16; ++kcl) {
      const unsigned word = (kcl < 8) ? q0[kcl >> 1] : q1[(kcl >> 1) - 4];
      const f16x8 a = expand8((word >> (sh0 + ((kcl & 1) << 4))) & 0xFFu);
      const f16x8 wh = *(const f16x8*)&WhL[((kw * 32 + kcl * 2 + hl) * 32 + l31) * 8];
      acch = MFMA32(a, wh, acch);
      accl = MFMA32(a, wlf[kcl], accl);
    }
    __builtin_amdgcn_s_setprio(0);
    f32x16 cb = acch + accl * inv4096;
    // C layout: col = lane&31, row = (reg&3) + 8*(reg>>2) + 4*hl; XOR-32 red (r11-proven)
    const int hl4 = hl * 4;
    const int xr = (l31 & 7) << 2;
#pragma unroll
    for (int rg = 0; rg < 4; ++rg) {
      f32x4 part = {cb[rg * 4 + 0], cb[rg * 4 + 1], cb[rg * 4 + 2], cb[rg * 4 + 3]};
      *(f32x4*)&pool[(kw * 32 + l31) * 32 + ((rg * 8 + hl4) ^ xr)] = part;
    }
    __syncthreads();
#pragma unroll
    for (int j = 0; j < 2; ++j) {
      const int o = j * 512 + tid;
      const int row = o >> 5, col = o & 31;
      const int rs = row ^ ((col & 7) << 2);
      float s = 0.0f;
#pragma unroll
      for (int p = 0; p < 8; ++p) s += pool[(p * 32 + col) * 32 + rs];
      cI[j] = s;
    }
  };
  // LIF + tagged spike stores (tag and bits in ONE u64: single-copy-atomic)
  auto lif = [&](const float (&cI)[2], const float (&Ix)[2], float (&V)[2],
                 unsigned (&cnt)[2], int g, int nbuf, unsigned tag, bool dostore) {
#pragma unroll
    for (int j = 0; j < 2; ++j) {
      float I = cI[j] + Ix[j];
      float v = 0.9f * V[j] + I;
      bool sp = (v - 1.0f) >= 0.0f;
      V[j] = sp ? 0.0f : v;
      cnt[j] += sp ? 1u : 0u;
      if (dostore) {
        unsigned long long ba = __ballot(sp);
        const int rowf = g * 32 + j * 16 + kw * 2;  // lanes 0-31: rowf, 32-63: rowf+1
        const unsigned long long tg = ((unsigned long long)tag) << 32;
        if (lane == 0)
          __hip_atomic_store(bmv + (size_t)nbuf * 16384 + (size_t)rowf * 64 + ns,
                             tg | (unsigned)ba, __ATOMIC_RELAXED, __HIP_MEMORY_SCOPE_AGENT);
        else if (lane == 32)
          __hip_atomic_store(bmv + (size_t)nbuf * 16384 + (size_t)(rowf + 1) * 64 + ns,
                             tg | (unsigned)(ba >> 32), __ATOMIC_RELAXED, __HIP_MEMORY_SCOPE_AGENT);
      }
    }
  };

  // ---------- t = 0: Iext-only LIF; spikes tagged 1 -> buf 1; prefetch A ----------
  {
    const float cz[2] = {0.f, 0.f};
    lif(cz, IxA, VA, cA, gA, 1, 1u, true);
    lif(cz, IxB, VB, cB, gB, 1, 1u, true);
    spec_issue(gA, 1, vA);
  }

  for (int t = 1; t < T_STEPS; ++t) {
    const int cbuf = t & 1, nbuf = (t + 1) & 1;
    const bool last = (t == T_STEPS - 1);
    float cI[2];

    // ---- phase A ----
    check_retry(gA, cbuf, (unsigned)t, vA);
    __syncthreads();                     // prior red reads done (and WhL load at t=1)
    stage(vA);
    __syncthreads();                     // bm staged
    spec_issue(gB, cbuf, vB);            // in flight under gemm(A)
    gemm(cI);
    lif(cI, IxA, VA, cA, gA, nbuf, (unsigned)(t + 1), !last);

    // ---- phase B ----
    check_retry(gB, cbuf, (unsigned)t, vB);
    __syncthreads();
    stage(vB);
    __syncthreads();
    if (!last) spec_issue(gA, nbuf, vA); // in flight under gemm(B)
    gemm(cI);
    lif(cI, IxB, VB, cB, gB, nbuf, (unsigned)(t + 1), !last);
  }

  // ---------- write firing rates ----------
#pragma unroll
  for (int j = 0; j < 2; ++j) {
    const int rA = gA * 32 + j * 16 + (tid >> 5);
    const int rB = gB * 32 + j * 16 + (tid >> 5);
    out[(size_t)rA * N_NEU + n0 + (tid & 31)] = (float)cA[j] * 0.015625f;
    out[(size_t)rB * N_NEU + n0 + (tid & 31)] = (float)cB[j] * 0.015625f;
  }
}

extern "C" void kernel_launch(void* const* d_in, const int* in_sizes, int n_in,
                              void* d_out, int out_size, void* d_ws, size_t ws_size,
                              hipStream_t stream) {
  (void)in_sizes; (void)n_in; (void)out_size; (void)ws_size;
  const float* ext  = (const float*)d_in[0];
  const float* Win  = (const float*)d_in[1];
  const float* bin  = (const float*)d_in[2];
  const float* adj  = (const float*)d_in[3];
  const float* mask = (const float*)d_in[4];
  unsigned char* ws = (unsigned char*)d_ws;

  _Float16* Wh   = (_Float16*)(ws);
  _Float16* Wl   = (_Float16*)(ws + (size_t)(8u << 20));
  float*    Iext = (float*)   (ws + (size_t)(16u << 20));
  unsigned long long* bmv = (unsigned long long*)(ws + (size_t)(18u << 20));
  float* out = (float*)d_out;

  hipLaunchKernelGGL(k_wsplit, dim3(2048), dim3(256), 0, stream, adj, mask, Wh, Wl, bmv);
  hipLaunchKernelGGL(k_iext,   dim3(128),  dim3(256), 0, stream, ext, Win, bin, Iext);
  hipLaunchKernelGGL(k_fused17, dim3(256), dim3(512), 0, stream,
                     Wh, Wl, Iext, bmv, out);
}